// Round 7
// baseline (263.896 us; speedup 1.0000x reference)
//
#include <hip/hip_runtime.h>

#define B_ 4
#define S_ 2048
#define D_ 768
#define H_ 12
#define HD_ 64
#define T_ (B_ * S_)  // 8192

typedef __bf16 bf16x8 __attribute__((ext_vector_type(8)));
typedef __bf16 bf16x4 __attribute__((ext_vector_type(4)));
typedef float  f32x4  __attribute__((ext_vector_type(4)));

__device__ __forceinline__ f32x4 mfma16(bf16x8 a, bf16x8 b, f32x4 c) {
  return __builtin_amdgcn_mfma_f32_16x16x32_bf16(a, b, c, 0, 0, 0);
}

// 2^x via v_exp_f32 (scores are pre-scaled by log2e at weight-convert time)
__device__ __forceinline__ float fexp2(float x) {
  float r;
  asm("v_exp_f32 %0, %1" : "=v"(r) : "v"(x));
  return r;
}

// async global->LDS, 16B per lane. LDS dest is wave-uniform base + lane*16.
__device__ __forceinline__ void gload16(const __bf16* g, __bf16* lds) {
  __builtin_amdgcn_global_load_lds(
      (__attribute__((address_space(1))) void*)g,
      (__attribute__((address_space(3))) void*)lds, 16, 0, 0);
}

// ---------------- fp32 -> bf16 convert (vectorized, optional scale) ----------
__global__ void cvt_f32_bf16(const float* __restrict__ in, __bf16* __restrict__ out,
                             int n4, float scale) {
  int i = blockIdx.x * blockDim.x + threadIdx.x;
  if (i >= n4) return;
  float4 v = reinterpret_cast<const float4*>(in)[i];
  bf16x4 o;
  o[0] = (__bf16)(v.x * scale);
  o[1] = (__bf16)(v.y * scale);
  o[2] = (__bf16)(v.z * scale);
  o[3] = (__bf16)(v.w * scale);
  reinterpret_cast<bf16x4*>(out)[i] = o;
}

// ---------------- GEMM: C[m][n] = sum_k A[m][k] * W[n][k]  (B^T layout) ------
template <int MODE>
__global__ __launch_bounds__(256, 2)
void gemm_bt(const __bf16* __restrict__ A,
             const __bf16* __restrict__ W0, const __bf16* __restrict__ W1,
             const __bf16* __restrict__ W2,
             __bf16* __restrict__ Oq, __bf16* __restrict__ Ok,
             __bf16* __restrict__ Ov,
             float* __restrict__ fout, const float* __restrict__ bias) {
  constexpr int K = D_;  // 768
  __shared__ __align__(16) __bf16 sA[128 * 32];
  __shared__ __align__(16) __bf16 sB[128 * 32];

  const int tid = threadIdx.x;
  const int l = tid & 63;
  const int w = tid >> 6;
  const int m0 = blockIdx.x * 128;

  int mat, n0;
  const __bf16* Wm;
  if (MODE == 0) {
    mat = blockIdx.y / 6;
    n0 = (blockIdx.y % 6) * 128;
    Wm = (mat == 0) ? W0 : (mat == 1) ? W1 : W2;
  } else {
    mat = 0;
    n0 = blockIdx.y * 128;
    Wm = W0;
  }

  const int srow = l >> 2;
  const int sk = (l & 3) * 8;
  const int c0 = w * 2, c1 = w * 2 + 1;
  const __bf16* gA0 = A + (m0 + c0 * 16 + srow) * K + sk;
  const __bf16* gA1 = A + (m0 + c1 * 16 + srow) * K + sk;
  const __bf16* gB0 = Wm + (n0 + c0 * 16 + srow) * K + sk;
  const __bf16* gB1 = Wm + (n0 + c1 * 16 + srow) * K + sk;
  __bf16* lA0 = &sA[c0 * 512];
  __bf16* lA1 = &sA[c1 * 512];
  __bf16* lB0 = &sB[c0 * 512];
  __bf16* lB1 = &sB[c1 * 512];

  f32x4 acc[4][4] = {};
  const int wr = w >> 1, wc = w & 1;
  const int fr = l & 15, fq = l >> 4;

  for (int kt = 0; kt < K / 32; ++kt) {
    const int ko = kt * 32;
    gload16(gA0 + ko, lA0);
    gload16(gA1 + ko, lA1);
    gload16(gB0 + ko, lB0);
    gload16(gB1 + ko, lB1);
    __syncthreads();
    bf16x8 af[4], bfr[4];
#pragma unroll
    for (int mi = 0; mi < 4; ++mi)
      af[mi] = *reinterpret_cast<const bf16x8*>(
          &sA[(wr * 64 + mi * 16 + fr) * 32 + fq * 8]);
#pragma unroll
    for (int ni = 0; ni < 4; ++ni)
      bfr[ni] = *reinterpret_cast<const bf16x8*>(
          &sB[(wc * 64 + ni * 16 + fr) * 32 + fq * 8]);
#pragma unroll
    for (int mi = 0; mi < 4; ++mi)
#pragma unroll
      for (int ni = 0; ni < 4; ++ni)
        acc[mi][ni] = mfma16(af[mi], bfr[ni], acc[mi][ni]);
    __syncthreads();
  }

#pragma unroll
  for (int mi = 0; mi < 4; ++mi) {
    const int mbase = m0 + wr * 64 + mi * 16 + fq * 4;
#pragma unroll
    for (int ni = 0; ni < 4; ++ni) {
      const int o = n0 + wc * 64 + ni * 16 + fr;
#pragma unroll
      for (int r = 0; r < 4; ++r) {
        const float v = acc[mi][ni][r];
        const int mm = mbase + r;
        if (MODE == 1) {
          fout[mm * D_ + o] = v + bias[o];
        } else {
          const int b = mm >> 11, s = mm & (S_ - 1);
          const int h = o >> 6, hd = o & 63;
          if (mat == 0)
            Oq[((size_t)((b * H_ + h) * S_ + s)) * HD_ + hd] = (__bf16)v;
          else if (mat == 1)
            Ok[((size_t)((b * H_ + h) * S_ + s)) * HD_ + hd] = (__bf16)v;
          else
            Ov[((size_t)((b * H_ + h) * HD_ + hd)) * S_ + s] = (__bf16)v;
        }
      }
    }
  }
}

// ---------------- causal flash attention, swapped-operand, QBLK=32 ------------
// grid = 3072 one-wave blocks. Block mapping: xcd = bx&7, j = bx>>3;
// head = xcd + 8*(j%6)  -> each XCD sees only 6 heads (3 MB K/V fits its L2);
// tile = 63 - j/6       -> deepest causal chains dispatch first.
// Per tile: QK^T (swapped, S^T) -> issue ALL V loads -> per q-group:
// lane-local softmax, P-stage through LDS, PV (swapped, O^T). g=1 softmax
// overlaps g=0's LDS round-trip + PV MFMAs. Scores are in log2-domain
// (log2e folded into K scale) so exp = single v_exp_f32.
__global__ __launch_bounds__(64, 4)
void attn_kernel(const __bf16* __restrict__ Q, const __bf16* __restrict__ Kt,
                 const __bf16* __restrict__ Vt, __bf16* __restrict__ C) {
  __shared__ __align__(16) __bf16 sP[32 * 64];  // 4 KB, swizzled
  const int l = threadIdx.x;
  const int fr = l & 15, fq = l >> 4;
  const int bx = blockIdx.x;
  const int xcd = bx & 7;
  const int j = bx >> 3;             // [0, 384)
  const int bh = xcd + 8 * (j % 6);  // head in [0, 48)
  const int tile = 63 - j / 6;       // [0, 64), deep first
  const int qb = tile * 32;

  const __bf16* qh = Q + (size_t)bh * S_ * HD_;
  const __bf16* kh = Kt + (size_t)bh * S_ * HD_;
  const __bf16* vh = Vt + (size_t)bh * HD_ * S_;
  char* sPb = reinterpret_cast<char*>(sP);

  // Q fragments (B-operand): group g covers q = qb + g*16 + fr
  bf16x8 qf[2][2];
#pragma unroll
  for (int g = 0; g < 2; ++g)
#pragma unroll
    for (int ks = 0; ks < 2; ++ks)
      qf[g][ks] = *reinterpret_cast<const bf16x8*>(
          &qh[(size_t)(qb + g * 16 + fr) * HD_ + ks * 32 + fq * 8]);

  // acc[g][dt][r] = O^T[d = dt*16 + fq*4 + r][q = qb + g*16 + fr]
  f32x4 acc[2][4] = {};
  float mrow[2] = {-1e30f, -1e30f}, lrow[2] = {0.f, 0.f};

  const int ntiles = (qb + 32 + 63) >> 6;  // ceil((qb+32)/64)
  for (int t = 0; t < ntiles; ++t) {
    const int kv0 = t << 6;

    // QK^T swapped, K loads shared by both q-groups:
    // s[g][c][r] = S[kv = kv0 + c*16 + fq*4 + r][q = qb + g*16 + fr]
    f32x4 s[2][4];
    __builtin_amdgcn_s_setprio(1);
#pragma unroll
    for (int c = 0; c < 4; ++c) {
      bf16x8 kf0 = *reinterpret_cast<const bf16x8*>(
          &kh[(size_t)(kv0 + c * 16 + fr) * HD_ + fq * 8]);
      bf16x8 kf1 = *reinterpret_cast<const bf16x8*>(
          &kh[(size_t)(kv0 + c * 16 + fr) * HD_ + 32 + fq * 8]);
#pragma unroll
      for (int g = 0; g < 2; ++g) {
        f32x4 z = {};
        z = mfma16(kf0, qf[g][0], z);
        z = mfma16(kf1, qf[g][1], z);
        s[g][c] = z;
      }
    }
    __builtin_amdgcn_s_setprio(0);

    // issue ALL V loads now: ~250 cy L2 latency hides under softmax + P-stage
    bf16x8 vf[4][2];
#pragma unroll
    for (int dt = 0; dt < 4; ++dt) {
      vf[dt][0] = *reinterpret_cast<const bf16x8*>(
          &vh[(size_t)(dt * 16 + fr) * S_ + kv0 + fq * 8]);
      vf[dt][1] = *reinterpret_cast<const bf16x8*>(
          &vh[(size_t)(dt * 16 + fr) * S_ + kv0 + 32 + fq * 8]);
    }

    if (kv0 + 63 > qb) {  // tile may contain masked elements (min q-row = qb)
#pragma unroll
      for (int g = 0; g < 2; ++g) {
        const int qi = qb + g * 16 + fr;
#pragma unroll
        for (int c = 0; c < 4; ++c)
#pragma unroll
          for (int r = 0; r < 4; ++r) {
            const int kvi = kv0 + c * 16 + fq * 4 + r;
            if (kvi > qi) s[g][c][r] = -1e30f;
          }
      }
    }

    // per q-group: lane-local softmax -> P-stage -> PV. g=1's VALU work
    // overlaps g=0's LDS round-trip and PV MFMAs (no barriers, 1 wave).
#pragma unroll
    for (int g = 0; g < 2; ++g) {
      float tm = -1e30f;
#pragma unroll
      for (int c = 0; c < 4; ++c)
#pragma unroll
        for (int r = 0; r < 4; ++r) tm = fmaxf(tm, s[g][c][r]);
      tm = fmaxf(tm, __shfl_xor(tm, 16));
      tm = fmaxf(tm, __shfl_xor(tm, 32));
      const float mn = fmaxf(mrow[g], tm);
      const float fac = fexp2(mrow[g] - mn);  // log2-domain
      mrow[g] = mn;
      float sum = 0.f;
#pragma unroll
      for (int c = 0; c < 4; ++c)
#pragma unroll
        for (int r = 0; r < 4; ++r) {
          const float p = fexp2(s[g][c][r] - mn);
          s[g][c][r] = p;
          sum += p;
        }
      sum += __shfl_xor(sum, 16);
      sum += __shfl_xor(sum, 32);
      lrow[g] = lrow[g] * fac + sum;
#pragma unroll
      for (int dt = 0; dt < 4; ++dt)
#pragma unroll
        for (int r = 0; r < 4; ++r) acc[g][dt][r] *= fac;  // lane-local fac

      // stage P -> LDS as P[q][kv], row = g*16 + fr, XOR-swizzle (fr&7)<<4
#pragma unroll
      for (int c = 0; c < 4; ++c) {
        bf16x4 pc;
#pragma unroll
        for (int r = 0; r < 4; ++r) pc[r] = (__bf16)s[g][c][r];
        const int bo = (c * 32 + fq * 8) ^ ((fr & 7) << 4);
        *reinterpret_cast<bf16x4*>(sPb + (g * 16 + fr) * 128 + bo) = pc;
      }
      // read P as A-fragment: row = q, k(kv) = ks*32 + fq*8 ..
      bf16x8 pa[2];
#pragma unroll
      for (int ks = 0; ks < 2; ++ks) {
        const int bo = (ks * 64 + fq * 16) ^ ((fr & 7) << 4);
        pa[ks] =
            *reinterpret_cast<const bf16x8*>(sPb + (g * 16 + fr) * 128 + bo);
      }

      // PV swapped: O^T[d][q] += V^T[d][kv] * P[kv][q]
      __builtin_amdgcn_s_setprio(1);
#pragma unroll
      for (int dt = 0; dt < 4; ++dt) {
        acc[g][dt] = mfma16(vf[dt][0], pa[0], acc[g][dt]);
        acc[g][dt] = mfma16(vf[dt][1], pa[1], acc[g][dt]);
      }
      __builtin_amdgcn_s_setprio(0);
    }
  }

  // epilogue: all lane-local. acc[g][dt][r] -> C[q][d = dt*16 + fq*4 + r]
  const int b = bh / H_, h = bh % H_;
#pragma unroll
  for (int g = 0; g < 2; ++g) {
    const float inv_l = 1.0f / lrow[g];
    const int qrow = qb + g * 16 + fr;
#pragma unroll
    for (int dt = 0; dt < 4; ++dt) {
      bf16x4 ov;
#pragma unroll
      for (int r = 0; r < 4; ++r) ov[r] = (__bf16)(acc[g][dt][r] * inv_l);
      *reinterpret_cast<bf16x4*>(
          &C[((size_t)(b * S_ + qrow)) * D_ + h * HD_ + dt * 16 + fq * 4]) =
          ov;
    }
  }
}

// ---------------- workspace layout (bf16 elements) ---------------------------
static constexpr size_t XB_OFF = 0;
static constexpr size_t WQ_OFF = XB_OFF + (size_t)T_ * D_;
static constexpr size_t WK_OFF = WQ_OFF + (size_t)D_ * D_;
static constexpr size_t WV_OFF = WK_OFF + (size_t)D_ * D_;
static constexpr size_t WO_OFF = WV_OFF + (size_t)D_ * D_;
static constexpr size_t Q_OFF = WO_OFF + (size_t)D_ * D_;
static constexpr size_t K_OFF = Q_OFF + (size_t)T_ * D_;
static constexpr size_t V_OFF = K_OFF + (size_t)T_ * D_;
static constexpr size_t C_OFF = V_OFF + (size_t)T_ * D_;

extern "C" void kernel_launch(void* const* d_in, const int* in_sizes, int n_in,
                              void* d_out, int out_size, void* d_ws,
                              size_t ws_size, hipStream_t stream) {
  const float* x = (const float*)d_in[0];
  const float* wq = (const float*)d_in[1];
  const float* wk = (const float*)d_in[2];
  const float* wv = (const float*)d_in[3];
  const float* wo = (const float*)d_in[4];
  const float* bo = (const float*)d_in[5];
  float* out = (float*)d_out;
  __bf16* ws = (__bf16*)d_ws;

  __bf16* xb = ws + XB_OFF;
  __bf16* wqb = ws + WQ_OFF;
  __bf16* wkb = ws + WK_OFF;
  __bf16* wvb = ws + WV_OFF;
  __bf16* wob = ws + WO_OFF;
  __bf16* qbuf = ws + Q_OFF;
  __bf16* kbuf = ws + K_OFF;
  __bf16* vbuf = ws + V_OFF;
  __bf16* cbuf = ws + C_OFF;

  {
    int n4 = T_ * D_ / 4;
    cvt_f32_bf16<<<(n4 + 255) / 256, 256, 0, stream>>>(x, xb, n4, 1.0f);
    n4 = D_ * D_ / 4;
    cvt_f32_bf16<<<(n4 + 255) / 256, 256, 0, stream>>>(wq, wqb, n4, 1.0f);
    // fold 1/sqrt(64) * log2(e) into K: scores emerge in log2-domain
    cvt_f32_bf16<<<(n4 + 255) / 256, 256, 0, stream>>>(wk, wkb, n4,
                                                       0.18033688f);
    cvt_f32_bf16<<<(n4 + 255) / 256, 256, 0, stream>>>(wv, wvb, n4, 1.0f);
    cvt_f32_bf16<<<(n4 + 255) / 256, 256, 0, stream>>>(wo, wob, n4, 1.0f);
  }

  gemm_bt<0><<<dim3(T_ / 128, 18), 256, 0, stream>>>(
      xb, wqb, wkb, wvb, qbuf, kbuf, vbuf, nullptr, nullptr);

  attn_kernel<<<dim3(3072), 64, 0, stream>>>(qbuf, kbuf, vbuf, cbuf);

  gemm_bt<1><<<dim3(T_ / 128, 6), 256, 0, stream>>>(
      cbuf, wob, nullptr, nullptr, nullptr, nullptr, nullptr, out, bo);
}

// Round 8
// 200.978 us; speedup vs baseline: 1.3131x; 1.3131x over previous
//
#include <hip/hip_runtime.h>

#define B_ 4
#define S_ 2048
#define D_ 768
#define H_ 12
#define HD_ 64
#define T_ (B_ * S_)  // 8192

typedef __bf16 bf16x8 __attribute__((ext_vector_type(8)));
typedef __bf16 bf16x4 __attribute__((ext_vector_type(4)));
typedef float  f32x4  __attribute__((ext_vector_type(4)));

__device__ __forceinline__ f32x4 mfma16(bf16x8 a, bf16x8 b, f32x4 c) {
  return __builtin_amdgcn_mfma_f32_16x16x32_bf16(a, b, c, 0, 0, 0);
}

// 2^x via v_exp_f32 (scores are pre-scaled by log2e at weight-convert time)
__device__ __forceinline__ float fexp2(float x) {
  float r;
  asm("v_exp_f32 %0, %1" : "=v"(r) : "v"(x));
  return r;
}

// async global->LDS, 16B per lane. LDS dest is wave-uniform base + lane*16.
__device__ __forceinline__ void gload16(const __bf16* g, __bf16* lds) {
  __builtin_amdgcn_global_load_lds(
      (__attribute__((address_space(1))) void*)g,
      (__attribute__((address_space(3))) void*)lds, 16, 0, 0);
}

// ---------------- fp32 -> bf16 convert (vectorized, optional scale) ----------
__global__ void cvt_f32_bf16(const float* __restrict__ in, __bf16* __restrict__ out,
                             int n4, float scale) {
  int i = blockIdx.x * blockDim.x + threadIdx.x;
  if (i >= n4) return;
  float4 v = reinterpret_cast<const float4*>(in)[i];
  bf16x4 o;
  o[0] = (__bf16)(v.x * scale);
  o[1] = (__bf16)(v.y * scale);
  o[2] = (__bf16)(v.z * scale);
  o[3] = (__bf16)(v.w * scale);
  reinterpret_cast<bf16x4*>(out)[i] = o;
}

// ---------------- GEMM: C[m][n] = sum_k A[m][k] * W[n][k]  (B^T layout) ------
template <int MODE>
__global__ __launch_bounds__(256, 2)
void gemm_bt(const __bf16* __restrict__ A,
             const __bf16* __restrict__ W0, const __bf16* __restrict__ W1,
             const __bf16* __restrict__ W2,
             __bf16* __restrict__ Oq, __bf16* __restrict__ Ok,
             __bf16* __restrict__ Ov,
             float* __restrict__ fout, const float* __restrict__ bias) {
  constexpr int K = D_;  // 768
  __shared__ __align__(16) __bf16 sA[128 * 32];
  __shared__ __align__(16) __bf16 sB[128 * 32];

  const int tid = threadIdx.x;
  const int l = tid & 63;
  const int w = tid >> 6;
  const int m0 = blockIdx.x * 128;

  int mat, n0;
  const __bf16* Wm;
  if (MODE == 0) {
    mat = blockIdx.y / 6;
    n0 = (blockIdx.y % 6) * 128;
    Wm = (mat == 0) ? W0 : (mat == 1) ? W1 : W2;
  } else {
    mat = 0;
    n0 = blockIdx.y * 128;
    Wm = W0;
  }

  const int srow = l >> 2;
  const int sk = (l & 3) * 8;
  const int c0 = w * 2, c1 = w * 2 + 1;
  const __bf16* gA0 = A + (m0 + c0 * 16 + srow) * K + sk;
  const __bf16* gA1 = A + (m0 + c1 * 16 + srow) * K + sk;
  const __bf16* gB0 = Wm + (n0 + c0 * 16 + srow) * K + sk;
  const __bf16* gB1 = Wm + (n0 + c1 * 16 + srow) * K + sk;
  __bf16* lA0 = &sA[c0 * 512];
  __bf16* lA1 = &sA[c1 * 512];
  __bf16* lB0 = &sB[c0 * 512];
  __bf16* lB1 = &sB[c1 * 512];

  f32x4 acc[4][4] = {};
  const int wr = w >> 1, wc = w & 1;
  const int fr = l & 15, fq = l >> 4;

  for (int kt = 0; kt < K / 32; ++kt) {
    const int ko = kt * 32;
    gload16(gA0 + ko, lA0);
    gload16(gA1 + ko, lA1);
    gload16(gB0 + ko, lB0);
    gload16(gB1 + ko, lB1);
    __syncthreads();
    bf16x8 af[4], bfr[4];
#pragma unroll
    for (int mi = 0; mi < 4; ++mi)
      af[mi] = *reinterpret_cast<const bf16x8*>(
          &sA[(wr * 64 + mi * 16 + fr) * 32 + fq * 8]);
#pragma unroll
    for (int ni = 0; ni < 4; ++ni)
      bfr[ni] = *reinterpret_cast<const bf16x8*>(
          &sB[(wc * 64 + ni * 16 + fr) * 32 + fq * 8]);
#pragma unroll
    for (int mi = 0; mi < 4; ++mi)
#pragma unroll
      for (int ni = 0; ni < 4; ++ni)
        acc[mi][ni] = mfma16(af[mi], bfr[ni], acc[mi][ni]);
    __syncthreads();
  }

#pragma unroll
  for (int mi = 0; mi < 4; ++mi) {
    const int mbase = m0 + wr * 64 + mi * 16 + fq * 4;
#pragma unroll
    for (int ni = 0; ni < 4; ++ni) {
      const int o = n0 + wc * 64 + ni * 16 + fr;
#pragma unroll
      for (int r = 0; r < 4; ++r) {
        const float v = acc[mi][ni][r];
        const int mm = mbase + r;
        if (MODE == 1) {
          fout[mm * D_ + o] = v + bias[o];
        } else {
          const int b = mm >> 11, s = mm & (S_ - 1);
          const int h = o >> 6, hd = o & 63;
          if (mat == 0)
            Oq[((size_t)((b * H_ + h) * S_ + s)) * HD_ + hd] = (__bf16)v;
          else if (mat == 1)
            Ok[((size_t)((b * H_ + h) * S_ + s)) * HD_ + hd] = (__bf16)v;
          else
            Ov[((size_t)((b * H_ + h) * HD_ + hd)) * S_ + s] = (__bf16)v;
        }
      }
    }
  }
}

// ---------------- causal flash attention, swapped-operand, QBLK=32 ------------
// grid = 3072 one-wave blocks. Block mapping: xcd = bx&7, j = bx>>3;
// head = xcd + 8*(j%6)  -> each XCD sees only 6 heads (3 MB K/V fits its L2);
// tile = 63 - j/6       -> deepest causal chains dispatch first.
// Per tile: QK^T (swapped, S^T) -> issue ALL V loads -> per q-group:
// lane-local softmax fused with bf16-pack + LDS store (frees f32 scores
// early), then PV (swapped, O^T). Scores in log2-domain (log2e folded into
// K scale) so exp = single v_exp_f32.
// amdgpu_waves_per_eu(3,4): grid gives only 3 waves/SIMD anyway; lets the
// allocator use ~168 VGPRs instead of spilling to hold an 8-wave allocation
// (round-7 lesson: WRITE_SIZE exploded 17->175 MB from scratch spill).
__global__ __launch_bounds__(64)
__attribute__((amdgpu_waves_per_eu(3, 4)))
void attn_kernel(const __bf16* __restrict__ Q, const __bf16* __restrict__ Kt,
                 const __bf16* __restrict__ Vt, __bf16* __restrict__ C) {
  __shared__ __align__(16) __bf16 sP[32 * 64];  // 4 KB, swizzled
  const int l = threadIdx.x;
  const int fr = l & 15, fq = l >> 4;
  const int bx = blockIdx.x;
  const int xcd = bx & 7;
  const int j = bx >> 3;             // [0, 384)
  const int bh = xcd + 8 * (j % 6);  // head in [0, 48)
  const int tile = 63 - j / 6;       // [0, 64), deep first
  const int qb = tile * 32;

  const __bf16* qh = Q + (size_t)bh * S_ * HD_;
  const __bf16* kh = Kt + (size_t)bh * S_ * HD_;
  const __bf16* vh = Vt + (size_t)bh * HD_ * S_;
  char* sPb = reinterpret_cast<char*>(sP);

  // Q fragments (B-operand): group g covers q = qb + g*16 + fr
  bf16x8 qf[2][2];
#pragma unroll
  for (int g = 0; g < 2; ++g)
#pragma unroll
    for (int ks = 0; ks < 2; ++ks)
      qf[g][ks] = *reinterpret_cast<const bf16x8*>(
          &qh[(size_t)(qb + g * 16 + fr) * HD_ + ks * 32 + fq * 8]);

  // acc[g][dt][r] = O^T[d = dt*16 + fq*4 + r][q = qb + g*16 + fr]
  f32x4 acc[2][4] = {};
  float mrow[2] = {-1e30f, -1e30f}, lrow[2] = {0.f, 0.f};

  const int ntiles = (qb + 32 + 63) >> 6;  // ceil((qb+32)/64)
  for (int t = 0; t < ntiles; ++t) {
    const int kv0 = t << 6;

    // QK^T swapped, K loads shared by both q-groups:
    // s[g][c][r] = S[kv = kv0 + c*16 + fq*4 + r][q = qb + g*16 + fr]
    f32x4 s[2][4];
    __builtin_amdgcn_s_setprio(1);
#pragma unroll
    for (int c = 0; c < 4; ++c) {
      bf16x8 kf0 = *reinterpret_cast<const bf16x8*>(
          &kh[(size_t)(kv0 + c * 16 + fr) * HD_ + fq * 8]);
      bf16x8 kf1 = *reinterpret_cast<const bf16x8*>(
          &kh[(size_t)(kv0 + c * 16 + fr) * HD_ + 32 + fq * 8]);
#pragma unroll
      for (int g = 0; g < 2; ++g) {
        f32x4 z = {};
        z = mfma16(kf0, qf[g][0], z);
        z = mfma16(kf1, qf[g][1], z);
        s[g][c] = z;
      }
    }
    __builtin_amdgcn_s_setprio(0);

    // issue ALL V loads now: ~250 cy L2 latency hides under softmax + P-stage
    bf16x8 vf[4][2];
#pragma unroll
    for (int dt = 0; dt < 4; ++dt) {
      vf[dt][0] = *reinterpret_cast<const bf16x8*>(
          &vh[(size_t)(dt * 16 + fr) * S_ + kv0 + fq * 8]);
      vf[dt][1] = *reinterpret_cast<const bf16x8*>(
          &vh[(size_t)(dt * 16 + fr) * S_ + kv0 + 32 + fq * 8]);
    }

    if (kv0 + 63 > qb) {  // tile may contain masked elements (min q-row = qb)
#pragma unroll
      for (int g = 0; g < 2; ++g) {
        const int qi = qb + g * 16 + fr;
#pragma unroll
        for (int c = 0; c < 4; ++c)
#pragma unroll
          for (int r = 0; r < 4; ++r) {
            const int kvi = kv0 + c * 16 + fq * 4 + r;
            if (kvi > qi) s[g][c][r] = -1e30f;
          }
      }
    }

    // per q-group: lane-local softmax fused with P-stage (frees s[g] before
    // PV), then PV. g=1's VALU overlaps g=0's LDS round-trip + PV MFMAs.
#pragma unroll
    for (int g = 0; g < 2; ++g) {
      float tm = -1e30f;
#pragma unroll
      for (int c = 0; c < 4; ++c)
#pragma unroll
        for (int r = 0; r < 4; ++r) tm = fmaxf(tm, s[g][c][r]);
      tm = fmaxf(tm, __shfl_xor(tm, 16));
      tm = fmaxf(tm, __shfl_xor(tm, 32));
      const float mn = fmaxf(mrow[g], tm);
      const float fac = fexp2(mrow[g] - mn);  // log2-domain
      mrow[g] = mn;
      float sum = 0.f;
      // exp -> pack bf16 -> LDS store per column; s[g][c] dies here
#pragma unroll
      for (int c = 0; c < 4; ++c) {
        bf16x4 pc;
#pragma unroll
        for (int r = 0; r < 4; ++r) {
          const float p = fexp2(s[g][c][r] - mn);
          sum += p;
          pc[r] = (__bf16)p;
        }
        const int bo = (c * 32 + fq * 8) ^ ((fr & 7) << 4);
        *reinterpret_cast<bf16x4*>(sPb + (g * 16 + fr) * 128 + bo) = pc;
      }
      sum += __shfl_xor(sum, 16);
      sum += __shfl_xor(sum, 32);
      lrow[g] = lrow[g] * fac + sum;
#pragma unroll
      for (int dt = 0; dt < 4; ++dt)
#pragma unroll
        for (int r = 0; r < 4; ++r) acc[g][dt][r] *= fac;  // lane-local fac

      // read P as A-fragment: row = q, k(kv) = ks*32 + fq*8 ..
      bf16x8 pa[2];
#pragma unroll
      for (int ks = 0; ks < 2; ++ks) {
        const int bo = (ks * 64 + fq * 16) ^ ((fr & 7) << 4);
        pa[ks] =
            *reinterpret_cast<const bf16x8*>(sPb + (g * 16 + fr) * 128 + bo);
      }

      // PV swapped: O^T[d][q] += V^T[d][kv] * P[kv][q]
      __builtin_amdgcn_s_setprio(1);
#pragma unroll
      for (int dt = 0; dt < 4; ++dt) {
        acc[g][dt] = mfma16(vf[dt][0], pa[0], acc[g][dt]);
        acc[g][dt] = mfma16(vf[dt][1], pa[1], acc[g][dt]);
      }
      __builtin_amdgcn_s_setprio(0);
    }
  }

  // epilogue: all lane-local. acc[g][dt][r] -> C[q][d = dt*16 + fq*4 + r]
  const int b = bh / H_, h = bh % H_;
#pragma unroll
  for (int g = 0; g < 2; ++g) {
    const float inv_l = 1.0f / lrow[g];
    const int qrow = qb + g * 16 + fr;
#pragma unroll
    for (int dt = 0; dt < 4; ++dt) {
      bf16x4 ov;
#pragma unroll
      for (int r = 0; r < 4; ++r) ov[r] = (__bf16)(acc[g][dt][r] * inv_l);
      *reinterpret_cast<bf16x4*>(
          &C[((size_t)(b * S_ + qrow)) * D_ + h * HD_ + dt * 16 + fq * 4]) =
          ov;
    }
  }
}

// ---------------- workspace layout (bf16 elements) ---------------------------
static constexpr size_t XB_OFF = 0;
static constexpr size_t WQ_OFF = XB_OFF + (size_t)T_ * D_;
static constexpr size_t WK_OFF = WQ_OFF + (size_t)D_ * D_;
static constexpr size_t WV_OFF = WK_OFF + (size_t)D_ * D_;
static constexpr size_t WO_OFF = WV_OFF + (size_t)D_ * D_;
static constexpr size_t Q_OFF = WO_OFF + (size_t)D_ * D_;
static constexpr size_t K_OFF = Q_OFF + (size_t)T_ * D_;
static constexpr size_t V_OFF = K_OFF + (size_t)T_ * D_;
static constexpr size_t C_OFF = V_OFF + (size_t)T_ * D_;

extern "C" void kernel_launch(void* const* d_in, const int* in_sizes, int n_in,
                              void* d_out, int out_size, void* d_ws,
                              size_t ws_size, hipStream_t stream) {
  const float* x = (const float*)d_in[0];
  const float* wq = (const float*)d_in[1];
  const float* wk = (const float*)d_in[2];
  const float* wv = (const float*)d_in[3];
  const float* wo = (const float*)d_in[4];
  const float* bo = (const float*)d_in[5];
  float* out = (float*)d_out;
  __bf16* ws = (__bf16*)d_ws;

  __bf16* xb = ws + XB_OFF;
  __bf16* wqb = ws + WQ_OFF;
  __bf16* wkb = ws + WK_OFF;
  __bf16* wvb = ws + WV_OFF;
  __bf16* wob = ws + WO_OFF;
  __bf16* qbuf = ws + Q_OFF;
  __bf16* kbuf = ws + K_OFF;
  __bf16* vbuf = ws + V_OFF;
  __bf16* cbuf = ws + C_OFF;

  {
    int n4 = T_ * D_ / 4;
    cvt_f32_bf16<<<(n4 + 255) / 256, 256, 0, stream>>>(x, xb, n4, 1.0f);
    n4 = D_ * D_ / 4;
    cvt_f32_bf16<<<(n4 + 255) / 256, 256, 0, stream>>>(wq, wqb, n4, 1.0f);
    // fold 1/sqrt(64) * log2(e) into K: scores emerge in log2-domain
    cvt_f32_bf16<<<(n4 + 255) / 256, 256, 0, stream>>>(wk, wkb, n4,
                                                       0.18033688f);
    cvt_f32_bf16<<<(n4 + 255) / 256, 256, 0, stream>>>(wv, wvb, n4, 1.0f);
    cvt_f32_bf16<<<(n4 + 255) / 256, 256, 0, stream>>>(wo, wob, n4, 1.0f);
  }

  gemm_bt<0><<<dim3(T_ / 128, 18), 256, 0, stream>>>(
      xb, wqb, wkb, wvb, qbuf, kbuf, vbuf, nullptr, nullptr);

  attn_kernel<<<dim3(3072), 64, 0, stream>>>(qbuf, kbuf, vbuf, cbuf);

  gemm_bt<1><<<dim3(T_ / 128, 6), 256, 0, stream>>>(
      cbuf, wob, nullptr, nullptr, nullptr, nullptr, nullptr, out, bo);
}

// Round 9
// 157.693 us; speedup vs baseline: 1.6735x; 1.2745x over previous
//
#include <hip/hip_runtime.h>

#define B_ 4
#define S_ 2048
#define D_ 768
#define H_ 12
#define HD_ 64
#define T_ (B_ * S_)  // 8192

typedef __bf16 bf16x8 __attribute__((ext_vector_type(8)));
typedef __bf16 bf16x4 __attribute__((ext_vector_type(4)));
typedef float  f32x4  __attribute__((ext_vector_type(4)));

__device__ __forceinline__ f32x4 mfma16(bf16x8 a, bf16x8 b, f32x4 c) {
  return __builtin_amdgcn_mfma_f32_16x16x32_bf16(a, b, c, 0, 0, 0);
}

// 2^x via v_exp_f32 (scores are pre-scaled by log2e at weight-convert time)
__device__ __forceinline__ float fexp2(float x) {
  float r;
  asm("v_exp_f32 %0, %1" : "=v"(r) : "v"(x));
  return r;
}

// async global->LDS, 16B per lane. LDS dest is wave-uniform base + lane*16.
__device__ __forceinline__ void gload16(const __bf16* g, __bf16* lds) {
  __builtin_amdgcn_global_load_lds(
      (__attribute__((address_space(1))) void*)g,
      (__attribute__((address_space(3))) void*)lds, 16, 0, 0);
}

// ---------------- fp32 -> bf16 convert (vectorized, optional scale) ----------
__global__ void cvt_f32_bf16(const float* __restrict__ in, __bf16* __restrict__ out,
                             int n4, float scale) {
  int i = blockIdx.x * blockDim.x + threadIdx.x;
  if (i >= n4) return;
  float4 v = reinterpret_cast<const float4*>(in)[i];
  bf16x4 o;
  o[0] = (__bf16)(v.x * scale);
  o[1] = (__bf16)(v.y * scale);
  o[2] = (__bf16)(v.z * scale);
  o[3] = (__bf16)(v.w * scale);
  reinterpret_cast<bf16x4*>(out)[i] = o;
}

// ---------------- GEMM: C[m][n] = sum_k A[m][k] * W[n][k]  (B^T layout) ------
template <int MODE>
__global__ __launch_bounds__(256, 2)
void gemm_bt(const __bf16* __restrict__ A,
             const __bf16* __restrict__ W0, const __bf16* __restrict__ W1,
             const __bf16* __restrict__ W2,
             __bf16* __restrict__ Oq, __bf16* __restrict__ Ok,
             __bf16* __restrict__ Ov,
             float* __restrict__ fout, const float* __restrict__ bias) {
  constexpr int K = D_;  // 768
  __shared__ __align__(16) __bf16 sA[128 * 32];
  __shared__ __align__(16) __bf16 sB[128 * 32];

  const int tid = threadIdx.x;
  const int l = tid & 63;
  const int w = tid >> 6;
  const int m0 = blockIdx.x * 128;

  int mat, n0;
  const __bf16* Wm;
  if (MODE == 0) {
    mat = blockIdx.y / 6;
    n0 = (blockIdx.y % 6) * 128;
    Wm = (mat == 0) ? W0 : (mat == 1) ? W1 : W2;
  } else {
    mat = 0;
    n0 = blockIdx.y * 128;
    Wm = W0;
  }

  const int srow = l >> 2;
  const int sk = (l & 3) * 8;
  const int c0 = w * 2, c1 = w * 2 + 1;
  const __bf16* gA0 = A + (m0 + c0 * 16 + srow) * K + sk;
  const __bf16* gA1 = A + (m0 + c1 * 16 + srow) * K + sk;
  const __bf16* gB0 = Wm + (n0 + c0 * 16 + srow) * K + sk;
  const __bf16* gB1 = Wm + (n0 + c1 * 16 + srow) * K + sk;
  __bf16* lA0 = &sA[c0 * 512];
  __bf16* lA1 = &sA[c1 * 512];
  __bf16* lB0 = &sB[c0 * 512];
  __bf16* lB1 = &sB[c1 * 512];

  f32x4 acc[4][4] = {};
  const int wr = w >> 1, wc = w & 1;
  const int fr = l & 15, fq = l >> 4;

  for (int kt = 0; kt < K / 32; ++kt) {
    const int ko = kt * 32;
    gload16(gA0 + ko, lA0);
    gload16(gA1 + ko, lA1);
    gload16(gB0 + ko, lB0);
    gload16(gB1 + ko, lB1);
    __syncthreads();
    bf16x8 af[4], bfr[4];
#pragma unroll
    for (int mi = 0; mi < 4; ++mi)
      af[mi] = *reinterpret_cast<const bf16x8*>(
          &sA[(wr * 64 + mi * 16 + fr) * 32 + fq * 8]);
#pragma unroll
    for (int ni = 0; ni < 4; ++ni)
      bfr[ni] = *reinterpret_cast<const bf16x8*>(
          &sB[(wc * 64 + ni * 16 + fr) * 32 + fq * 8]);
#pragma unroll
    for (int mi = 0; mi < 4; ++mi)
#pragma unroll
      for (int ni = 0; ni < 4; ++ni)
        acc[mi][ni] = mfma16(af[mi], bfr[ni], acc[mi][ni]);
    __syncthreads();
  }

#pragma unroll
  for (int mi = 0; mi < 4; ++mi) {
    const int mbase = m0 + wr * 64 + mi * 16 + fq * 4;
#pragma unroll
    for (int ni = 0; ni < 4; ++ni) {
      const int o = n0 + wc * 64 + ni * 16 + fr;
#pragma unroll
      for (int r = 0; r < 4; ++r) {
        const float v = acc[mi][ni][r];
        const int mm = mbase + r;
        if (MODE == 1) {
          fout[mm * D_ + o] = v + bias[o];
        } else {
          const int b = mm >> 11, s = mm & (S_ - 1);
          const int h = o >> 6, hd = o & 63;
          if (mat == 0)
            Oq[((size_t)((b * H_ + h) * S_ + s)) * HD_ + hd] = (__bf16)v;
          else if (mat == 1)
            Ok[((size_t)((b * H_ + h) * S_ + s)) * HD_ + hd] = (__bf16)v;
          else
            Ov[((size_t)((b * H_ + h) * HD_ + hd)) * S_ + s] = (__bf16)v;
        }
      }
    }
  }
}

// ---------------- causal flash attention: 4-warp block, LDS-staged K/V --------
// grid = 768 blocks (16 q-tiles x 48 heads) of 256 threads (4 warps x 32 q).
// Mapping: xcd = bx&7, j = bx>>3; head = xcd + 8*(j%6) (6 heads/XCD -> K/V
// L2-local); qtile = 15 - j/6 (deep first). Per KV tile (64): K and V^T are
// staged ONCE into LDS (double-buffered; stage t+1 issued before computing t,
// one barrier per tile) and shared by all 4 warps -> K/V traffic /4 and loads
// off the critical path. LDS tiles are XOR-swizzled via pre-swizzled global
// source (gload_lds writes linearly; swizzle applied on src + ds_read side).
// Per-warp inner loop: swapped QK^T (S^T, lane owns q-row), lane-local
// log2-domain softmax fused with bf16 pack -> P LDS tile, swapped PV (O^T).
__global__ __launch_bounds__(256)
__attribute__((amdgpu_waves_per_eu(3, 4)))
void attn_kernel(const __bf16* __restrict__ Q, const __bf16* __restrict__ Kt,
                 const __bf16* __restrict__ Vt, __bf16* __restrict__ C) {
  __shared__ __align__(16) __bf16 sK[2][64 * 64];  // [kv][hd], swizzled
  __shared__ __align__(16) __bf16 sV[2][64 * 64];  // V^T [hd][kv], swizzled
  __shared__ __align__(16) __bf16 sP[4][32 * 64];  // per-warp P, swizzled

  const int tid = threadIdx.x;
  const int l = tid & 63;
  const int w = tid >> 6;
  const int fr = l & 15, fq = l >> 4;
  const int bx = blockIdx.x;
  const int xcd = bx & 7;
  const int j = bx >> 3;             // [0, 96)
  const int bh = xcd + 8 * (j % 6);  // head in [0, 48)
  const int qtile = 15 - j / 6;      // [0, 16), deep first
  const int qb = qtile * 128;
  const int qbw = qb + w * 32;  // this warp's 32 q-rows

  const __bf16* qh = Q + (size_t)bh * S_ * HD_;
  const __bf16* kh = Kt + (size_t)bh * S_ * HD_;
  const __bf16* vh = Vt + (size_t)bh * HD_ * S_;
  char* sPb = reinterpret_cast<char*>(&sP[w][0]);

  // staging lane constants: lane l of chunk q writes LDS row q*8 + (l>>3),
  // 16B slot (l&7); source column pre-swizzled so LDS[row][x] = G[row][x^swz]
  const int srow = l >> 3;                          // 0..7
  const int scol = ((l & 7) * 8) ^ (srow << 3);     // elements, 0..56
  const int swz = (fr & 7) << 4;                    // read-side XOR (bytes)

  // Q fragments (B-operand): group g covers q = qbw + g*16 + fr
  bf16x8 qf[2][2];
#pragma unroll
  for (int g = 0; g < 2; ++g)
#pragma unroll
    for (int ks = 0; ks < 2; ++ks)
      qf[g][ks] = *reinterpret_cast<const bf16x8*>(
          &qh[(size_t)(qbw + g * 16 + fr) * HD_ + ks * 32 + fq * 8]);

  // acc[g][dt][r] = O^T[d = dt*16 + fq*4 + r][q = qbw + g*16 + fr]
  f32x4 acc[2][4] = {};
  float mrow[2] = {-1e30f, -1e30f}, lrow[2] = {0.f, 0.f};

  const int nt = qb / 64 + 2;  // ceil((qb+128)/64)
  int cur = 0;

  // stage tile 0: warp w stages K chunks {2w,2w+1} and V chunks {2w,2w+1}
  {
    const int q0 = 2 * w, q1 = 2 * w + 1;
    gload16(kh + (size_t)(q0 * 8 + srow) * HD_ + scol, &sK[0][q0 * 512]);
    gload16(kh + (size_t)(q1 * 8 + srow) * HD_ + scol, &sK[0][q1 * 512]);
    gload16(vh + (size_t)(q0 * 8 + srow) * S_ + scol, &sV[0][q0 * 512]);
    gload16(vh + (size_t)(q1 * 8 + srow) * S_ + scol, &sV[0][q1 * 512]);
  }
  __syncthreads();

  for (int t = 0; t < nt; ++t) {
    const int kv0 = t * 64;
    // issue next tile's stage into the other buffer (latency hides under
    // this tile's compute; the end-of-loop barrier drains it)
    if (t + 1 < nt) {
      const int kvn = kv0 + 64;
      const int q0 = 2 * w, q1 = 2 * w + 1;
      gload16(kh + (size_t)(kvn + q0 * 8 + srow) * HD_ + scol,
              &sK[cur ^ 1][q0 * 512]);
      gload16(kh + (size_t)(kvn + q1 * 8 + srow) * HD_ + scol,
              &sK[cur ^ 1][q1 * 512]);
      gload16(vh + (size_t)(q0 * 8 + srow) * S_ + kvn + scol,
              &sV[cur ^ 1][q0 * 512]);
      gload16(vh + (size_t)(q1 * 8 + srow) * S_ + kvn + scol,
              &sV[cur ^ 1][q1 * 512]);
    }

    if (kv0 <= qbw + 31) {  // this warp has unmasked work in this tile
      const char* kb = reinterpret_cast<const char*>(&sK[cur][0]);
      const char* vb = reinterpret_cast<const char*>(&sV[cur][0]);

      // QK^T swapped: s[g][c][r] = S[kv = kv0+c*16+fq*4+r][q = qbw+g*16+fr]
      f32x4 s[2][4];
      __builtin_amdgcn_s_setprio(1);
#pragma unroll
      for (int c = 0; c < 4; ++c) {
        const int row = c * 16 + fr;
        bf16x8 kf0 = *reinterpret_cast<const bf16x8*>(
            kb + row * 128 + ((fq * 16) ^ swz));
        bf16x8 kf1 = *reinterpret_cast<const bf16x8*>(
            kb + row * 128 + ((fq * 16 + 64) ^ swz));
#pragma unroll
        for (int g = 0; g < 2; ++g) {
          f32x4 z = {};
          z = mfma16(kf0, qf[g][0], z);
          z = mfma16(kf1, qf[g][1], z);
          s[g][c] = z;
        }
      }
      __builtin_amdgcn_s_setprio(0);

      if (kv0 + 63 > qbw) {  // tile may contain masked elements
#pragma unroll
        for (int g = 0; g < 2; ++g) {
          const int qi = qbw + g * 16 + fr;
#pragma unroll
          for (int c = 0; c < 4; ++c)
#pragma unroll
            for (int r = 0; r < 4; ++r) {
              const int kvi = kv0 + c * 16 + fq * 4 + r;
              if (kvi > qi) s[g][c][r] = -1e30f;
            }
        }
      }

      // per q-group: lane-local softmax fused with P-stage, then PV
#pragma unroll
      for (int g = 0; g < 2; ++g) {
        float tm = -1e30f;
#pragma unroll
        for (int c = 0; c < 4; ++c)
#pragma unroll
          for (int r = 0; r < 4; ++r) tm = fmaxf(tm, s[g][c][r]);
        tm = fmaxf(tm, __shfl_xor(tm, 16));
        tm = fmaxf(tm, __shfl_xor(tm, 32));
        const float mn = fmaxf(mrow[g], tm);
        const float fac = fexp2(mrow[g] - mn);  // log2-domain
        mrow[g] = mn;
        float sum = 0.f;
#pragma unroll
        for (int c = 0; c < 4; ++c) {
          bf16x4 pc;
#pragma unroll
          for (int r = 0; r < 4; ++r) {
            const float p = fexp2(s[g][c][r] - mn);
            sum += p;
            pc[r] = (__bf16)p;
          }
          const int bo = (c * 32 + fq * 8) ^ swz;
          *reinterpret_cast<bf16x4*>(sPb + (g * 16 + fr) * 128 + bo) = pc;
        }
        sum += __shfl_xor(sum, 16);
        sum += __shfl_xor(sum, 32);
        lrow[g] = lrow[g] * fac + sum;
#pragma unroll
        for (int dt = 0; dt < 4; ++dt)
#pragma unroll
          for (int r = 0; r < 4; ++r) acc[g][dt][r] *= fac;

        bf16x8 pa[2];
#pragma unroll
        for (int ks = 0; ks < 2; ++ks) {
          const int bo = (ks * 64 + fq * 16) ^ swz;
          pa[ks] = *reinterpret_cast<const bf16x8*>(sPb +
                                                    (g * 16 + fr) * 128 + bo);
        }

        // PV swapped: O^T[d][q] += V^T[d][kv] * P[kv][q]; V from LDS
        __builtin_amdgcn_s_setprio(1);
#pragma unroll
        for (int dt = 0; dt < 4; ++dt) {
          const int row = dt * 16 + fr;
          bf16x8 vf0 = *reinterpret_cast<const bf16x8*>(
              vb + row * 128 + ((fq * 16) ^ swz));
          bf16x8 vf1 = *reinterpret_cast<const bf16x8*>(
              vb + row * 128 + ((fq * 16 + 64) ^ swz));
          acc[g][dt] = mfma16(vf0, pa[0], acc[g][dt]);
          acc[g][dt] = mfma16(vf1, pa[1], acc[g][dt]);
        }
        __builtin_amdgcn_s_setprio(0);
      }
    }

    __syncthreads();  // all warps done with buf[cur]; stage of buf[cur^1] done
    cur ^= 1;
  }

  // epilogue: all lane-local. acc[g][dt][r] -> C[q][d = dt*16 + fq*4 + r]
  const int b = bh / H_, h = bh % H_;
#pragma unroll
  for (int g = 0; g < 2; ++g) {
    const float inv_l = 1.0f / lrow[g];
    const int qrow = qbw + g * 16 + fr;
#pragma unroll
    for (int dt = 0; dt < 4; ++dt) {
      bf16x4 ov;
#pragma unroll
      for (int r = 0; r < 4; ++r) ov[r] = (__bf16)(acc[g][dt][r] * inv_l);
      *reinterpret_cast<bf16x4*>(
          &C[((size_t)(b * S_ + qrow)) * D_ + h * HD_ + dt * 16 + fq * 4]) =
          ov;
    }
  }
}

// ---------------- workspace layout (bf16 elements) ---------------------------
static constexpr size_t XB_OFF = 0;
static constexpr size_t WQ_OFF = XB_OFF + (size_t)T_ * D_;
static constexpr size_t WK_OFF = WQ_OFF + (size_t)D_ * D_;
static constexpr size_t WV_OFF = WK_OFF + (size_t)D_ * D_;
static constexpr size_t WO_OFF = WV_OFF + (size_t)D_ * D_;
static constexpr size_t Q_OFF = WO_OFF + (size_t)D_ * D_;
static constexpr size_t K_OFF = Q_OFF + (size_t)T_ * D_;
static constexpr size_t V_OFF = K_OFF + (size_t)T_ * D_;
static constexpr size_t C_OFF = V_OFF + (size_t)T_ * D_;

extern "C" void kernel_launch(void* const* d_in, const int* in_sizes, int n_in,
                              void* d_out, int out_size, void* d_ws,
                              size_t ws_size, hipStream_t stream) {
  const float* x = (const float*)d_in[0];
  const float* wq = (const float*)d_in[1];
  const float* wk = (const float*)d_in[2];
  const float* wv = (const float*)d_in[3];
  const float* wo = (const float*)d_in[4];
  const float* bo = (const float*)d_in[5];
  float* out = (float*)d_out;
  __bf16* ws = (__bf16*)d_ws;

  __bf16* xb = ws + XB_OFF;
  __bf16* wqb = ws + WQ_OFF;
  __bf16* wkb = ws + WK_OFF;
  __bf16* wvb = ws + WV_OFF;
  __bf16* wob = ws + WO_OFF;
  __bf16* qbuf = ws + Q_OFF;
  __bf16* kbuf = ws + K_OFF;
  __bf16* vbuf = ws + V_OFF;
  __bf16* cbuf = ws + C_OFF;

  {
    int n4 = T_ * D_ / 4;
    cvt_f32_bf16<<<(n4 + 255) / 256, 256, 0, stream>>>(x, xb, n4, 1.0f);
    n4 = D_ * D_ / 4;
    cvt_f32_bf16<<<(n4 + 255) / 256, 256, 0, stream>>>(wq, wqb, n4, 1.0f);
    // fold 1/sqrt(64) * log2(e) into K: scores emerge in log2-domain
    cvt_f32_bf16<<<(n4 + 255) / 256, 256, 0, stream>>>(wk, wkb, n4,
                                                       0.18033688f);
    cvt_f32_bf16<<<(n4 + 255) / 256, 256, 0, stream>>>(wv, wvb, n4, 1.0f);
    cvt_f32_bf16<<<(n4 + 255) / 256, 256, 0, stream>>>(wo, wob, n4, 1.0f);
  }

  gemm_bt<0><<<dim3(T_ / 128, 18), 256, 0, stream>>>(
      xb, wqb, wkb, wvb, qbuf, kbuf, vbuf, nullptr, nullptr);

  attn_kernel<<<dim3(768), 256, 0, stream>>>(qbuf, kbuf, vbuf, cbuf);

  gemm_bt<1><<<dim3(T_ / 128, 6), 256, 0, stream>>>(
      cbuf, wob, nullptr, nullptr, nullptr, nullptr, nullptr, out, bo);
}

// Round 10
// 156.298 us; speedup vs baseline: 1.6884x; 1.0089x over previous
//
#include <hip/hip_runtime.h>

#define B_ 4
#define S_ 2048
#define D_ 768
#define H_ 12
#define HD_ 64
#define T_ (B_ * S_)  // 8192

typedef __bf16 bf16x8 __attribute__((ext_vector_type(8)));
typedef __bf16 bf16x4 __attribute__((ext_vector_type(4)));
typedef float  f32x4  __attribute__((ext_vector_type(4)));

__device__ __forceinline__ f32x4 mfma16(bf16x8 a, bf16x8 b, f32x4 c) {
  return __builtin_amdgcn_mfma_f32_16x16x32_bf16(a, b, c, 0, 0, 0);
}

// 2^x via v_exp_f32 (scores are pre-scaled by log2e at weight-convert time)
__device__ __forceinline__ float fexp2(float x) {
  float r;
  asm("v_exp_f32 %0, %1" : "=v"(r) : "v"(x));
  return r;
}

// async global->LDS, 16B per lane. LDS dest is wave-uniform base + lane*16.
__device__ __forceinline__ void gload16(const __bf16* g, __bf16* lds) {
  __builtin_amdgcn_global_load_lds(
      (__attribute__((address_space(1))) void*)g,
      (__attribute__((address_space(3))) void*)lds, 16, 0, 0);
}

// ---------------- fp32 -> bf16 convert (vectorized, optional scale) ----------
__global__ void cvt_f32_bf16(const float* __restrict__ in, __bf16* __restrict__ out,
                             int n4, float scale) {
  int i = blockIdx.x * blockDim.x + threadIdx.x;
  if (i >= n4) return;
  float4 v = reinterpret_cast<const float4*>(in)[i];
  bf16x4 o;
  o[0] = (__bf16)(v.x * scale);
  o[1] = (__bf16)(v.y * scale);
  o[2] = (__bf16)(v.z * scale);
  o[3] = (__bf16)(v.w * scale);
  reinterpret_cast<bf16x4*>(out)[i] = o;
}

// ---------------- GEMM: C[m][n] = sum_k A[m][k] * W[n][k]  (B^T layout) ------
// 128x128 tile, BK=64, double-buffered LDS with stage(t+1)-before-compute(t)
// (T3 minimum 2-phase: load latency hides under ds_read+MFMA instead of being
// drained by a barrier right after issue — round-9 lesson, MfmaUtil was 12%).
// LDS rows are 128 B, XOR-swizzled (row&7)<<4 via pre-swizzled global source
// (gload_lds writes linearly) + swizzled ds_read.
template <int MODE>
__global__ __launch_bounds__(256)
__attribute__((amdgpu_waves_per_eu(2)))
void gemm_bt(const __bf16* __restrict__ A,
             const __bf16* __restrict__ W0, const __bf16* __restrict__ W1,
             const __bf16* __restrict__ W2,
             __bf16* __restrict__ Oq, __bf16* __restrict__ Ok,
             __bf16* __restrict__ Ov,
             float* __restrict__ fout, const float* __restrict__ bias) {
  constexpr int K = D_;   // 768
  constexpr int NT = K / 64;  // 12 K-tiles
  __shared__ __align__(16) __bf16 sA[2][128 * 64];
  __shared__ __align__(16) __bf16 sB[2][128 * 64];

  const int tid = threadIdx.x;
  const int l = tid & 63;
  const int w = tid >> 6;
  const int m0 = blockIdx.x * 128;

  int mat, n0;
  const __bf16* Wm;
  if (MODE == 0) {
    mat = blockIdx.y / 6;
    n0 = (blockIdx.y % 6) * 128;
    Wm = (mat == 0) ? W0 : (mat == 1) ? W1 : W2;
  } else {
    mat = 0;
    n0 = blockIdx.y * 128;
    Wm = W0;
  }

  // staging: chunk c (0..15) = rows [c*8, c*8+8) x 64 k (1 KB). Wave w stages
  // chunks 4w..4w+3 of A and B. Lane l -> row c*8 + (l>>3), 16B slot (l&7);
  // source col pre-swizzled so LDS[r][slot] = G[r][slot ^ (r&7)].
  const int srow = l >> 3;                 // 0..7
  const int scol = ((l & 7) ^ srow) * 8;   // source col (elements)
  const __bf16* gA[4];
  const __bf16* gB[4];
#pragma unroll
  for (int i = 0; i < 4; ++i) {
    const int c = w * 4 + i;
    gA[i] = A + (size_t)(m0 + c * 8 + srow) * K + scol;
    gB[i] = Wm + (size_t)(n0 + c * 8 + srow) * K + scol;
  }

  f32x4 acc[4][4] = {};
  const int wr = w >> 1, wc = w & 1;
  const int fr = l & 15, fq = l >> 4;
  const int swz = (fr & 7) << 4;

  // prologue: stage K-tile 0 into buffer 0
#pragma unroll
  for (int i = 0; i < 4; ++i) {
    const int c = w * 4 + i;
    gload16(gA[i], &sA[0][c * 512]);
    gload16(gB[i], &sB[0][c * 512]);
  }
  __syncthreads();

  int cur = 0;
  for (int kt = 0; kt < NT; ++kt) {
    // issue next tile's stage first: latency hides under this tile's compute
    if (kt + 1 < NT) {
      const int ko = (kt + 1) * 64;
#pragma unroll
      for (int i = 0; i < 4; ++i) {
        const int c = w * 4 + i;
        gload16(gA[i] + ko, &sA[cur ^ 1][c * 512]);
        gload16(gB[i] + ko, &sB[cur ^ 1][c * 512]);
      }
    }
    const char* ab = reinterpret_cast<const char*>(&sA[cur][0]);
    const char* bb = reinterpret_cast<const char*>(&sB[cur][0]);
#pragma unroll
    for (int ks = 0; ks < 2; ++ks) {
      bf16x8 af[4], bfr[4];
#pragma unroll
      for (int mi = 0; mi < 4; ++mi)
        af[mi] = *reinterpret_cast<const bf16x8*>(
            ab + (wr * 64 + mi * 16 + fr) * 128 +
            ((ks * 64 + fq * 16) ^ swz));
#pragma unroll
      for (int ni = 0; ni < 4; ++ni)
        bfr[ni] = *reinterpret_cast<const bf16x8*>(
            bb + (wc * 64 + ni * 16 + fr) * 128 +
            ((ks * 64 + fq * 16) ^ swz));
#pragma unroll
      for (int mi = 0; mi < 4; ++mi)
#pragma unroll
        for (int ni = 0; ni < 4; ++ni)
          acc[mi][ni] = mfma16(af[mi], bfr[ni], acc[mi][ni]);
    }
    __syncthreads();  // publishes buf[cur^1] (vmcnt drain) + protects buf[cur]
    cur ^= 1;
  }

#pragma unroll
  for (int mi = 0; mi < 4; ++mi) {
    const int mbase = m0 + wr * 64 + mi * 16 + fq * 4;
#pragma unroll
    for (int ni = 0; ni < 4; ++ni) {
      const int o = n0 + wc * 64 + ni * 16 + fr;
#pragma unroll
      for (int r = 0; r < 4; ++r) {
        const float v = acc[mi][ni][r];
        const int mm = mbase + r;
        if (MODE == 1) {
          fout[mm * D_ + o] = v + bias[o];
        } else {
          const int b = mm >> 11, s = mm & (S_ - 1);
          const int h = o >> 6, hd = o & 63;
          if (mat == 0)
            Oq[((size_t)((b * H_ + h) * S_ + s)) * HD_ + hd] = (__bf16)v;
          else if (mat == 1)
            Ok[((size_t)((b * H_ + h) * S_ + s)) * HD_ + hd] = (__bf16)v;
          else
            Ov[((size_t)((b * H_ + h) * HD_ + hd)) * S_ + s] = (__bf16)v;
        }
      }
    }
  }
}

// ---------------- causal flash attention: 4-warp block, LDS-staged K/V --------
// grid = 768 blocks (16 q-tiles x 48 heads) of 256 threads (4 warps x 32 q).
// Mapping: xcd = bx&7, j = bx>>3; head = xcd + 8*(j%6) (6 heads/XCD -> K/V
// L2-local); qtile = 15 - j/6 (deep first). Per KV tile (64): K and V^T are
// staged ONCE into LDS (double-buffered; stage t+1 issued before computing t,
// one barrier per tile) and shared by all 4 warps. Swapped QK^T / PV with
// lane-local log2-domain softmax.
__global__ __launch_bounds__(256)
__attribute__((amdgpu_waves_per_eu(3, 4)))
void attn_kernel(const __bf16* __restrict__ Q, const __bf16* __restrict__ Kt,
                 const __bf16* __restrict__ Vt, __bf16* __restrict__ C) {
  __shared__ __align__(16) __bf16 sK[2][64 * 64];  // [kv][hd], swizzled
  __shared__ __align__(16) __bf16 sV[2][64 * 64];  // V^T [hd][kv], swizzled
  __shared__ __align__(16) __bf16 sP[4][32 * 64];  // per-warp P, swizzled

  const int tid = threadIdx.x;
  const int l = tid & 63;
  const int w = tid >> 6;
  const int fr = l & 15, fq = l >> 4;
  const int bx = blockIdx.x;
  const int xcd = bx & 7;
  const int j = bx >> 3;             // [0, 96)
  const int bh = xcd + 8 * (j % 6);  // head in [0, 48)
  const int qtile = 15 - j / 6;      // [0, 16), deep first
  const int qb = qtile * 128;
  const int qbw = qb + w * 32;  // this warp's 32 q-rows

  const __bf16* qh = Q + (size_t)bh * S_ * HD_;
  const __bf16* kh = Kt + (size_t)bh * S_ * HD_;
  const __bf16* vh = Vt + (size_t)bh * HD_ * S_;
  char* sPb = reinterpret_cast<char*>(&sP[w][0]);

  const int srow = l >> 3;                       // 0..7
  const int scol = ((l & 7) * 8) ^ (srow << 3);  // pre-swizzled source col
  const int swz = (fr & 7) << 4;                 // read-side XOR (bytes)

  bf16x8 qf[2][2];
#pragma unroll
  for (int g = 0; g < 2; ++g)
#pragma unroll
    for (int ks = 0; ks < 2; ++ks)
      qf[g][ks] = *reinterpret_cast<const bf16x8*>(
          &qh[(size_t)(qbw + g * 16 + fr) * HD_ + ks * 32 + fq * 8]);

  f32x4 acc[2][4] = {};
  float mrow[2] = {-1e30f, -1e30f}, lrow[2] = {0.f, 0.f};

  const int nt = qb / 64 + 2;  // ceil((qb+128)/64)
  int cur = 0;

  {
    const int q0 = 2 * w, q1 = 2 * w + 1;
    gload16(kh + (size_t)(q0 * 8 + srow) * HD_ + scol, &sK[0][q0 * 512]);
    gload16(kh + (size_t)(q1 * 8 + srow) * HD_ + scol, &sK[0][q1 * 512]);
    gload16(vh + (size_t)(q0 * 8 + srow) * S_ + scol, &sV[0][q0 * 512]);
    gload16(vh + (size_t)(q1 * 8 + srow) * S_ + scol, &sV[0][q1 * 512]);
  }
  __syncthreads();

  for (int t = 0; t < nt; ++t) {
    const int kv0 = t * 64;
    if (t + 1 < nt) {
      const int kvn = kv0 + 64;
      const int q0 = 2 * w, q1 = 2 * w + 1;
      gload16(kh + (size_t)(kvn + q0 * 8 + srow) * HD_ + scol,
              &sK[cur ^ 1][q0 * 512]);
      gload16(kh + (size_t)(kvn + q1 * 8 + srow) * HD_ + scol,
              &sK[cur ^ 1][q1 * 512]);
      gload16(vh + (size_t)(q0 * 8 + srow) * S_ + kvn + scol,
              &sV[cur ^ 1][q0 * 512]);
      gload16(vh + (size_t)(q1 * 8 + srow) * S_ + kvn + scol,
              &sV[cur ^ 1][q1 * 512]);
    }

    if (kv0 <= qbw + 31) {
      const char* kb = reinterpret_cast<const char*>(&sK[cur][0]);
      const char* vb = reinterpret_cast<const char*>(&sV[cur][0]);

      f32x4 s[2][4];
      __builtin_amdgcn_s_setprio(1);
#pragma unroll
      for (int c = 0; c < 4; ++c) {
        const int row = c * 16 + fr;
        bf16x8 kf0 = *reinterpret_cast<const bf16x8*>(
            kb + row * 128 + ((fq * 16) ^ swz));
        bf16x8 kf1 = *reinterpret_cast<const bf16x8*>(
            kb + row * 128 + ((fq * 16 + 64) ^ swz));
#pragma unroll
        for (int g = 0; g < 2; ++g) {
          f32x4 z = {};
          z = mfma16(kf0, qf[g][0], z);
          z = mfma16(kf1, qf[g][1], z);
          s[g][c] = z;
        }
      }
      __builtin_amdgcn_s_setprio(0);

      if (kv0 + 63 > qbw) {
#pragma unroll
        for (int g = 0; g < 2; ++g) {
          const int qi = qbw + g * 16 + fr;
#pragma unroll
          for (int c = 0; c < 4; ++c)
#pragma unroll
            for (int r = 0; r < 4; ++r) {
              const int kvi = kv0 + c * 16 + fq * 4 + r;
              if (kvi > qi) s[g][c][r] = -1e30f;
            }
        }
      }

#pragma unroll
      for (int g = 0; g < 2; ++g) {
        float tm = -1e30f;
#pragma unroll
        for (int c = 0; c < 4; ++c)
#pragma unroll
          for (int r = 0; r < 4; ++r) tm = fmaxf(tm, s[g][c][r]);
        tm = fmaxf(tm, __shfl_xor(tm, 16));
        tm = fmaxf(tm, __shfl_xor(tm, 32));
        const float mn = fmaxf(mrow[g], tm);
        const float fac = fexp2(mrow[g] - mn);  // log2-domain
        mrow[g] = mn;
        float sum = 0.f;
#pragma unroll
        for (int c = 0; c < 4; ++c) {
          bf16x4 pc;
#pragma unroll
          for (int r = 0; r < 4; ++r) {
            const float p = fexp2(s[g][c][r] - mn);
            sum += p;
            pc[r] = (__bf16)p;
          }
          const int bo = (c * 32 + fq * 8) ^ swz;
          *reinterpret_cast<bf16x4*>(sPb + (g * 16 + fr) * 128 + bo) = pc;
        }
        sum += __shfl_xor(sum, 16);
        sum += __shfl_xor(sum, 32);
        lrow[g] = lrow[g] * fac + sum;
#pragma unroll
        for (int dt = 0; dt < 4; ++dt)
#pragma unroll
          for (int r = 0; r < 4; ++r) acc[g][dt][r] *= fac;

        bf16x8 pa[2];
#pragma unroll
        for (int ks = 0; ks < 2; ++ks) {
          const int bo = (ks * 64 + fq * 16) ^ swz;
          pa[ks] = *reinterpret_cast<const bf16x8*>(sPb +
                                                    (g * 16 + fr) * 128 + bo);
        }

        __builtin_amdgcn_s_setprio(1);
#pragma unroll
        for (int dt = 0; dt < 4; ++dt) {
          const int row = dt * 16 + fr;
          bf16x8 vf0 = *reinterpret_cast<const bf16x8*>(
              vb + row * 128 + ((fq * 16) ^ swz));
          bf16x8 vf1 = *reinterpret_cast<const bf16x8*>(
              vb + row * 128 + ((fq * 16 + 64) ^ swz));
          acc[g][dt] = mfma16(vf0, pa[0], acc[g][dt]);
          acc[g][dt] = mfma16(vf1, pa[1], acc[g][dt]);
        }
        __builtin_amdgcn_s_setprio(0);
      }
    }

    __syncthreads();
    cur ^= 1;
  }

  const int b = bh / H_, h = bh % H_;
#pragma unroll
  for (int g = 0; g < 2; ++g) {
    const float inv_l = 1.0f / lrow[g];
    const int qrow = qbw + g * 16 + fr;
#pragma unroll
    for (int dt = 0; dt < 4; ++dt) {
      bf16x4 ov;
#pragma unroll
      for (int r = 0; r < 4; ++r) ov[r] = (__bf16)(acc[g][dt][r] * inv_l);
      *reinterpret_cast<bf16x4*>(
          &C[((size_t)(b * S_ + qrow)) * D_ + h * HD_ + dt * 16 + fq * 4]) =
          ov;
    }
  }
}

// ---------------- workspace layout (bf16 elements) ---------------------------
static constexpr size_t XB_OFF = 0;
static constexpr size_t WQ_OFF = XB_OFF + (size_t)T_ * D_;
static constexpr size_t WK_OFF = WQ_OFF + (size_t)D_ * D_;
static constexpr size_t WV_OFF = WK_OFF + (size_t)D_ * D_;
static constexpr size_t WO_OFF = WV_OFF + (size_t)D_ * D_;
static constexpr size_t Q_OFF = WO_OFF + (size_t)D_ * D_;
static constexpr size_t K_OFF = Q_OFF + (size_t)T_ * D_;
static constexpr size_t V_OFF = K_OFF + (size_t)T_ * D_;
static constexpr size_t C_OFF = V_OFF + (size_t)T_ * D_;

extern "C" void kernel_launch(void* const* d_in, const int* in_sizes, int n_in,
                              void* d_out, int out_size, void* d_ws,
                              size_t ws_size, hipStream_t stream) {
  const float* x = (const float*)d_in[0];
  const float* wq = (const float*)d_in[1];
  const float* wk = (const float*)d_in[2];
  const float* wv = (const float*)d_in[3];
  const float* wo = (const float*)d_in[4];
  const float* bo = (const float*)d_in[5];
  float* out = (float*)d_out;
  __bf16* ws = (__bf16*)d_ws;

  __bf16* xb = ws + XB_OFF;
  __bf16* wqb = ws + WQ_OFF;
  __bf16* wkb = ws + WK_OFF;
  __bf16* wvb = ws + WV_OFF;
  __bf16* wob = ws + WO_OFF;
  __bf16* qbuf = ws + Q_OFF;
  __bf16* kbuf = ws + K_OFF;
  __bf16* vbuf = ws + V_OFF;
  __bf16* cbuf = ws + C_OFF;

  {
    int n4 = T_ * D_ / 4;
    cvt_f32_bf16<<<(n4 + 255) / 256, 256, 0, stream>>>(x, xb, n4, 1.0f);
    n4 = D_ * D_ / 4;
    cvt_f32_bf16<<<(n4 + 255) / 256, 256, 0, stream>>>(wq, wqb, n4, 1.0f);
    // fold 1/sqrt(64) * log2(e) into K: scores emerge in log2-domain
    cvt_f32_bf16<<<(n4 + 255) / 256, 256, 0, stream>>>(wk, wkb, n4,
                                                       0.18033688f);
    cvt_f32_bf16<<<(n4 + 255) / 256, 256, 0, stream>>>(wv, wvb, n4, 1.0f);
    cvt_f32_bf16<<<(n4 + 255) / 256, 256, 0, stream>>>(wo, wob, n4, 1.0f);
  }

  gemm_bt<0><<<dim3(T_ / 128, 18), 256, 0, stream>>>(
      xb, wqb, wkb, wvb, qbuf, kbuf, vbuf, nullptr, nullptr);

  attn_kernel<<<dim3(768), 256, 0, stream>>>(qbuf, kbuf, vbuf, cbuf);

  gemm_bt<1><<<dim3(T_ / 128, 6), 256, 0, stream>>>(
      cbuf, wob, nullptr, nullptr, nullptr, nullptr, nullptr, out, bo);
}

// Round 11
// 146.498 us; speedup vs baseline: 1.8014x; 1.0669x over previous
//
#include <hip/hip_runtime.h>

#define B_ 4
#define S_ 2048
#define D_ 768
#define H_ 12
#define HD_ 64
#define T_ (B_ * S_)  // 8192

typedef __bf16 bf16x8 __attribute__((ext_vector_type(8)));
typedef __bf16 bf16x4 __attribute__((ext_vector_type(4)));
typedef float  f32x4  __attribute__((ext_vector_type(4)));

__device__ __forceinline__ f32x4 mfma16(bf16x8 a, bf16x8 b, f32x4 c) {
  return __builtin_amdgcn_mfma_f32_16x16x32_bf16(a, b, c, 0, 0, 0);
}

// 2^x via v_exp_f32 (scores are pre-scaled by log2e at weight-convert time)
__device__ __forceinline__ float fexp2(float x) {
  float r;
  asm("v_exp_f32 %0, %1" : "=v"(r) : "v"(x));
  return r;
}

// async global->LDS, 16B per lane. LDS dest is wave-uniform base + lane*16.
__device__ __forceinline__ void gload16(const __bf16* g, __bf16* lds) {
  __builtin_amdgcn_global_load_lds(
      (__attribute__((address_space(1))) void*)g,
      (__attribute__((address_space(3))) void*)lds, 16, 0, 0);
}

// ---------------- fp32 -> bf16 convert (vectorized, optional scale) ----------
__global__ void cvt_f32_bf16(const float* __restrict__ in, __bf16* __restrict__ out,
                             int n4, float scale) {
  int i = blockIdx.x * blockDim.x + threadIdx.x;
  if (i >= n4) return;
  float4 v = reinterpret_cast<const float4*>(in)[i];
  bf16x4 o;
  o[0] = (__bf16)(v.x * scale);
  o[1] = (__bf16)(v.y * scale);
  o[2] = (__bf16)(v.z * scale);
  o[3] = (__bf16)(v.w * scale);
  reinterpret_cast<bf16x4*>(out)[i] = o;
}

// ---------------- GEMM: C[m][n] = sum_k A[m][k] * W[n][k]  (B^T layout) ------
// 128x128 tile, BK=64, double-buffered LDS, COUNTED-vmcnt pipeline (T4):
// prologue stages tiles 0,1; each iteration waits vmcnt(8) (own stage(t)
// landed, stage(t+1) still in flight), raw-barriers, computes t, barriers,
// then stages t+2 into the freed buffer. vmcnt never drains to 0 mid-loop
// (round-10 lesson: __syncthreads' vmcnt(0) drain pinned MfmaUtil at 12%
// regardless of buffering — m233/m218 counted-vmcnt is the fix).
// LDS rows 128 B, XOR-swizzled (row&7)<<4 via pre-swizzled global source.
template <int MODE>
__global__ __launch_bounds__(256)
__attribute__((amdgpu_waves_per_eu(2)))
void gemm_bt(const __bf16* __restrict__ A,
             const __bf16* __restrict__ W0, const __bf16* __restrict__ W1,
             const __bf16* __restrict__ W2,
             __bf16* __restrict__ Oq, __bf16* __restrict__ Ok,
             __bf16* __restrict__ Ov,
             float* __restrict__ fout, const float* __restrict__ bias) {
  constexpr int K = D_;       // 768
  constexpr int NT = K / 64;  // 12 K-tiles
  __shared__ __align__(16) __bf16 sA[2][128 * 64];
  __shared__ __align__(16) __bf16 sB[2][128 * 64];

  const int tid = threadIdx.x;
  const int l = tid & 63;
  const int w = tid >> 6;
  const int m0 = blockIdx.x * 128;

  int mat, n0;
  const __bf16* Wm;
  if (MODE == 0) {
    mat = blockIdx.y / 6;
    n0 = (blockIdx.y % 6) * 128;
    Wm = (mat == 0) ? W0 : (mat == 1) ? W1 : W2;
  } else {
    mat = 0;
    n0 = blockIdx.y * 128;
    Wm = W0;
  }

  // staging: chunk c (0..15) = rows [c*8, c*8+8) x 64 k (1 KB). Wave w stages
  // chunks 4w..4w+3 of A and B. Lane l -> row c*8 + (l>>3), 16B slot (l&7);
  // source col pre-swizzled so LDS[r][slot] = G[r][slot ^ (r&7)].
  const int srow = l >> 3;                // 0..7
  const int scol = ((l & 7) ^ srow) * 8;  // source col (elements)
  const __bf16* gA[4];
  const __bf16* gB[4];
#pragma unroll
  for (int i = 0; i < 4; ++i) {
    const int c = w * 4 + i;
    gA[i] = A + (size_t)(m0 + c * 8 + srow) * K + scol;
    gB[i] = Wm + (size_t)(n0 + c * 8 + srow) * K + scol;
  }

  f32x4 acc[4][4] = {};
  const int wr = w >> 1, wc = w & 1;
  const int fr = l & 15, fq = l >> 4;
  const int swz = (fr & 7) << 4;

  // prologue: stage K-tiles 0 and 1 (16 loads/wave in flight)
#pragma unroll
  for (int i = 0; i < 4; ++i) {
    const int c = w * 4 + i;
    gload16(gA[i], &sA[0][c * 512]);
    gload16(gB[i], &sB[0][c * 512]);
  }
#pragma unroll
  for (int i = 0; i < 4; ++i) {
    const int c = w * 4 + i;
    gload16(gA[i] + 64, &sA[1][c * 512]);
    gload16(gB[i] + 64, &sB[1][c * 512]);
  }

  int cur = 0;
  for (int kt = 0; kt < NT; ++kt) {
    // wait for OWN stage(kt) only; stage(kt+1) stays in flight (counted vmcnt)
    if (kt + 1 < NT)
      asm volatile("s_waitcnt vmcnt(8)" ::: "memory");
    else
      asm volatile("s_waitcnt vmcnt(0)" ::: "memory");
    __builtin_amdgcn_s_barrier();  // all waves' stage(kt) landed

    const char* ab = reinterpret_cast<const char*>(&sA[cur][0]);
    const char* bb = reinterpret_cast<const char*>(&sB[cur][0]);
#pragma unroll
    for (int ks = 0; ks < 2; ++ks) {
      bf16x8 af[4], bfr[4];
#pragma unroll
      for (int mi = 0; mi < 4; ++mi)
        af[mi] = *reinterpret_cast<const bf16x8*>(
            ab + (wr * 64 + mi * 16 + fr) * 128 +
            ((ks * 64 + fq * 16) ^ swz));
#pragma unroll
      for (int ni = 0; ni < 4; ++ni)
        bfr[ni] = *reinterpret_cast<const bf16x8*>(
            bb + (wc * 64 + ni * 16 + fr) * 128 +
            ((ks * 64 + fq * 16) ^ swz));
#pragma unroll
      for (int mi = 0; mi < 4; ++mi)
#pragma unroll
        for (int ni = 0; ni < 4; ++ni)
          acc[mi][ni] = mfma16(af[mi], bfr[ni], acc[mi][ni]);
    }
    __builtin_amdgcn_s_barrier();  // all waves done reading buf[cur]

    // stage kt+2 into the buffer just freed (2-deep pipeline)
    if (kt + 2 < NT) {
      const int ko = (kt + 2) * 64;
#pragma unroll
      for (int i = 0; i < 4; ++i) {
        const int c = w * 4 + i;
        gload16(gA[i] + ko, &sA[cur][c * 512]);
        gload16(gB[i] + ko, &sB[cur][c * 512]);
      }
    }
    cur ^= 1;
  }

#pragma unroll
  for (int mi = 0; mi < 4; ++mi) {
    const int mbase = m0 + wr * 64 + mi * 16 + fq * 4;
#pragma unroll
    for (int ni = 0; ni < 4; ++ni) {
      const int o = n0 + wc * 64 + ni * 16 + fr;
#pragma unroll
      for (int r = 0; r < 4; ++r) {
        const float v = acc[mi][ni][r];
        const int mm = mbase + r;
        if (MODE == 1) {
          fout[mm * D_ + o] = v + bias[o];
        } else {
          const int b = mm >> 11, s = mm & (S_ - 1);
          const int h = o >> 6, hd = o & 63;
          if (mat == 0)
            Oq[((size_t)((b * H_ + h) * S_ + s)) * HD_ + hd] = (__bf16)v;
          else if (mat == 1)
            Ok[((size_t)((b * H_ + h) * S_ + s)) * HD_ + hd] = (__bf16)v;
          else
            Ov[((size_t)((b * H_ + h) * HD_ + hd)) * S_ + s] = (__bf16)v;
        }
      }
    }
  }
}

// ---------------- causal flash attention: 4-warp block, LDS-staged K/V --------
// grid = 768 blocks (16 q-tiles x 48 heads) of 256 threads (4 warps x 32 q).
// Mapping: xcd = bx&7, j = bx>>3; head = xcd + 8*(j%6) (6 heads/XCD -> K/V
// L2-local); qtile = 15 - j/6 (deep first). Per KV tile (64): K and V^T are
// staged ONCE into LDS (double-buffered; stage t+1 issued before computing t,
// one barrier per tile) and shared by all 4 warps. Swapped QK^T / PV with
// lane-local log2-domain softmax.
__global__ __launch_bounds__(256)
__attribute__((amdgpu_waves_per_eu(3, 4)))
void attn_kernel(const __bf16* __restrict__ Q, const __bf16* __restrict__ Kt,
                 const __bf16* __restrict__ Vt, __bf16* __restrict__ C) {
  __shared__ __align__(16) __bf16 sK[2][64 * 64];  // [kv][hd], swizzled
  __shared__ __align__(16) __bf16 sV[2][64 * 64];  // V^T [hd][kv], swizzled
  __shared__ __align__(16) __bf16 sP[4][32 * 64];  // per-warp P, swizzled

  const int tid = threadIdx.x;
  const int l = tid & 63;
  const int w = tid >> 6;
  const int fr = l & 15, fq = l >> 4;
  const int bx = blockIdx.x;
  const int xcd = bx & 7;
  const int j = bx >> 3;             // [0, 96)
  const int bh = xcd + 8 * (j % 6);  // head in [0, 48)
  const int qtile = 15 - j / 6;      // [0, 16), deep first
  const int qb = qtile * 128;
  const int qbw = qb + w * 32;  // this warp's 32 q-rows

  const __bf16* qh = Q + (size_t)bh * S_ * HD_;
  const __bf16* kh = Kt + (size_t)bh * S_ * HD_;
  const __bf16* vh = Vt + (size_t)bh * HD_ * S_;
  char* sPb = reinterpret_cast<char*>(&sP[w][0]);

  const int srow = l >> 3;                       // 0..7
  const int scol = ((l & 7) * 8) ^ (srow << 3);  // pre-swizzled source col
  const int swz = (fr & 7) << 4;                 // read-side XOR (bytes)

  bf16x8 qf[2][2];
#pragma unroll
  for (int g = 0; g < 2; ++g)
#pragma unroll
    for (int ks = 0; ks < 2; ++ks)
      qf[g][ks] = *reinterpret_cast<const bf16x8*>(
          &qh[(size_t)(qbw + g * 16 + fr) * HD_ + ks * 32 + fq * 8]);

  f32x4 acc[2][4] = {};
  float mrow[2] = {-1e30f, -1e30f}, lrow[2] = {0.f, 0.f};

  const int nt = qb / 64 + 2;  // ceil((qb+128)/64)
  int cur = 0;

  {
    const int q0 = 2 * w, q1 = 2 * w + 1;
    gload16(kh + (size_t)(q0 * 8 + srow) * HD_ + scol, &sK[0][q0 * 512]);
    gload16(kh + (size_t)(q1 * 8 + srow) * HD_ + scol, &sK[0][q1 * 512]);
    gload16(vh + (size_t)(q0 * 8 + srow) * S_ + scol, &sV[0][q0 * 512]);
    gload16(vh + (size_t)(q1 * 8 + srow) * S_ + scol, &sV[0][q1 * 512]);
  }
  __syncthreads();

  for (int t = 0; t < nt; ++t) {
    const int kv0 = t * 64;
    if (t + 1 < nt) {
      const int kvn = kv0 + 64;
      const int q0 = 2 * w, q1 = 2 * w + 1;
      gload16(kh + (size_t)(kvn + q0 * 8 + srow) * HD_ + scol,
              &sK[cur ^ 1][q0 * 512]);
      gload16(kh + (size_t)(kvn + q1 * 8 + srow) * HD_ + scol,
              &sK[cur ^ 1][q1 * 512]);
      gload16(vh + (size_t)(q0 * 8 + srow) * S_ + kvn + scol,
              &sV[cur ^ 1][q0 * 512]);
      gload16(vh + (size_t)(q1 * 8 + srow) * S_ + kvn + scol,
              &sV[cur ^ 1][q1 * 512]);
    }

    if (kv0 <= qbw + 31) {
      const char* kb = reinterpret_cast<const char*>(&sK[cur][0]);
      const char* vb = reinterpret_cast<const char*>(&sV[cur][0]);

      f32x4 s[2][4];
      __builtin_amdgcn_s_setprio(1);
#pragma unroll
      for (int c = 0; c < 4; ++c) {
        const int row = c * 16 + fr;
        bf16x8 kf0 = *reinterpret_cast<const bf16x8*>(
            kb + row * 128 + ((fq * 16) ^ swz));
        bf16x8 kf1 = *reinterpret_cast<const bf16x8*>(
            kb + row * 128 + ((fq * 16 + 64) ^ swz));
#pragma unroll
        for (int g = 0; g < 2; ++g) {
          f32x4 z = {};
          z = mfma16(kf0, qf[g][0], z);
          z = mfma16(kf1, qf[g][1], z);
          s[g][c] = z;
        }
      }
      __builtin_amdgcn_s_setprio(0);

      if (kv0 + 63 > qbw) {
#pragma unroll
        for (int g = 0; g < 2; ++g) {
          const int qi = qbw + g * 16 + fr;
#pragma unroll
          for (int c = 0; c < 4; ++c)
#pragma unroll
            for (int r = 0; r < 4; ++r) {
              const int kvi = kv0 + c * 16 + fq * 4 + r;
              if (kvi > qi) s[g][c][r] = -1e30f;
            }
        }
      }

#pragma unroll
      for (int g = 0; g < 2; ++g) {
        float tm = -1e30f;
#pragma unroll
        for (int c = 0; c < 4; ++c)
#pragma unroll
          for (int r = 0; r < 4; ++r) tm = fmaxf(tm, s[g][c][r]);
        tm = fmaxf(tm, __shfl_xor(tm, 16));
        tm = fmaxf(tm, __shfl_xor(tm, 32));
        const float mn = fmaxf(mrow[g], tm);
        const float fac = fexp2(mrow[g] - mn);  // log2-domain
        mrow[g] = mn;
        float sum = 0.f;
#pragma unroll
        for (int c = 0; c < 4; ++c) {
          bf16x4 pc;
#pragma unroll
          for (int r = 0; r < 4; ++r) {
            const float p = fexp2(s[g][c][r] - mn);
            sum += p;
            pc[r] = (__bf16)p;
          }
          const int bo = (c * 32 + fq * 8) ^ swz;
          *reinterpret_cast<bf16x4*>(sPb + (g * 16 + fr) * 128 + bo) = pc;
        }
        sum += __shfl_xor(sum, 16);
        sum += __shfl_xor(sum, 32);
        lrow[g] = lrow[g] * fac + sum;
#pragma unroll
        for (int dt = 0; dt < 4; ++dt)
#pragma unroll
          for (int r = 0; r < 4; ++r) acc[g][dt][r] *= fac;

        bf16x8 pa[2];
#pragma unroll
        for (int ks = 0; ks < 2; ++ks) {
          const int bo = (ks * 64 + fq * 16) ^ swz;
          pa[ks] = *reinterpret_cast<const bf16x8*>(sPb +
                                                    (g * 16 + fr) * 128 + bo);
        }

        __builtin_amdgcn_s_setprio(1);
#pragma unroll
        for (int dt = 0; dt < 4; ++dt) {
          const int row = dt * 16 + fr;
          bf16x8 vf0 = *reinterpret_cast<const bf16x8*>(
              vb + row * 128 + ((fq * 16) ^ swz));
          bf16x8 vf1 = *reinterpret_cast<const bf16x8*>(
              vb + row * 128 + ((fq * 16 + 64) ^ swz));
          acc[g][dt] = mfma16(vf0, pa[0], acc[g][dt]);
          acc[g][dt] = mfma16(vf1, pa[1], acc[g][dt]);
        }
        __builtin_amdgcn_s_setprio(0);
      }
    }

    __syncthreads();
    cur ^= 1;
  }

  const int b = bh / H_, h = bh % H_;
#pragma unroll
  for (int g = 0; g < 2; ++g) {
    const float inv_l = 1.0f / lrow[g];
    const int qrow = qbw + g * 16 + fr;
#pragma unroll
    for (int dt = 0; dt < 4; ++dt) {
      bf16x4 ov;
#pragma unroll
      for (int r = 0; r < 4; ++r) ov[r] = (__bf16)(acc[g][dt][r] * inv_l);
      *reinterpret_cast<bf16x4*>(
          &C[((size_t)(b * S_ + qrow)) * D_ + h * HD_ + dt * 16 + fq * 4]) =
          ov;
    }
  }
}

// ---------------- workspace layout (bf16 elements) ---------------------------
static constexpr size_t XB_OFF = 0;
static constexpr size_t WQ_OFF = XB_OFF + (size_t)T_ * D_;
static constexpr size_t WK_OFF = WQ_OFF + (size_t)D_ * D_;
static constexpr size_t WV_OFF = WK_OFF + (size_t)D_ * D_;
static constexpr size_t WO_OFF = WV_OFF + (size_t)D_ * D_;
static constexpr size_t Q_OFF = WO_OFF + (size_t)D_ * D_;
static constexpr size_t K_OFF = Q_OFF + (size_t)T_ * D_;
static constexpr size_t V_OFF = K_OFF + (size_t)T_ * D_;
static constexpr size_t C_OFF = V_OFF + (size_t)T_ * D_;

extern "C" void kernel_launch(void* const* d_in, const int* in_sizes, int n_in,
                              void* d_out, int out_size, void* d_ws,
                              size_t ws_size, hipStream_t stream) {
  const float* x = (const float*)d_in[0];
  const float* wq = (const float*)d_in[1];
  const float* wk = (const float*)d_in[2];
  const float* wv = (const float*)d_in[3];
  const float* wo = (const float*)d_in[4];
  const float* bo = (const float*)d_in[5];
  float* out = (float*)d_out;
  __bf16* ws = (__bf16*)d_ws;

  __bf16* xb = ws + XB_OFF;
  __bf16* wqb = ws + WQ_OFF;
  __bf16* wkb = ws + WK_OFF;
  __bf16* wvb = ws + WV_OFF;
  __bf16* wob = ws + WO_OFF;
  __bf16* qbuf = ws + Q_OFF;
  __bf16* kbuf = ws + K_OFF;
  __bf16* vbuf = ws + V_OFF;
  __bf16* cbuf = ws + C_OFF;

  {
    int n4 = T_ * D_ / 4;
    cvt_f32_bf16<<<(n4 + 255) / 256, 256, 0, stream>>>(x, xb, n4, 1.0f);
    n4 = D_ * D_ / 4;
    cvt_f32_bf16<<<(n4 + 255) / 256, 256, 0, stream>>>(wq, wqb, n4, 1.0f);
    // fold 1/sqrt(64) * log2(e) into K: scores emerge in log2-domain
    cvt_f32_bf16<<<(n4 + 255) / 256, 256, 0, stream>>>(wk, wkb, n4,
                                                       0.18033688f);
    cvt_f32_bf16<<<(n4 + 255) / 256, 256, 0, stream>>>(wv, wvb, n4, 1.0f);
    cvt_f32_bf16<<<(n4 + 255) / 256, 256, 0, stream>>>(wo, wob, n4, 1.0f);
  }

  gemm_bt<0><<<dim3(T_ / 128, 18), 256, 0, stream>>>(
      xb, wqb, wkb, wvb, qbuf, kbuf, vbuf, nullptr, nullptr);

  attn_kernel<<<dim3(768), 256, 0, stream>>>(qbuf, kbuf, vbuf, cbuf);

  gemm_bt<1><<<dim3(T_ / 128, 6), 256, 0, stream>>>(
      cbuf, wob, nullptr, nullptr, nullptr, nullptr, nullptr, out, bo);
}